// Round 1
// baseline (354.319 us; speedup 1.0000x reference)
//
#include <hip/hip_runtime.h>
#include <math.h>

// Problem constants: y is (8, 3, 256, 512) fp32, lmbd is (1,3).
#define TVW 512      // row length
#define TVH 256      // H (for channel index)
#define TVC 3        // channels
#define WPB 2        // waves (= rows) per block; 3072 blocks -> 12 blk/CU, 24 waves/CU
#define BLOCK (WPB * 64)

// One wave per row; all 64 lanes redundantly run the same row's Condat state
// machine with wave-uniform (ballot-scalar) control flow.
// v4: flattened single event-driven loop:
//  - no inner counted loop -> no trips/readfirstlane/pointer re-setup per event
//  - integer state (k,k0,km,kp,den) uniform via ballot selects -> SGPRs/SALU
//  - clamp adjust without compares: g = u_t - clamp(u_t)  (bitwise-identical)
//  - jump detect: single fmax(-umin_t, umax_t) > lam
//  - rn reset after events is the constant 0.5f (== rtab[2])
// Output built in place in the LDS row; one coalesced float4 writeback.
__global__ __launch_bounds__(BLOCK)
void tv1d_condat_wave_kernel(const float* __restrict__ y,
                             const float* __restrict__ lmbd,
                             float* __restrict__ out,
                             int total_rows) {
    __shared__ __align__(16) float buf[WPB * TVW + 4];
    __shared__ float rtab[520];        // rtab[i] = 1/i (i>=1)
    const int tid  = threadIdx.x;
    const int wave = tid >> 6;
    const int lane = tid & 63;
    const int base_row = blockIdx.x * WPB;
    const int row = base_row + wave;

    // ---- stage WPB contiguous rows into LDS (coalesced float4) + recip table ----
    {
        float4* b4 = (float4*)buf;
        const float4* s4 = (const float4*)(y + (size_t)base_row * TVW);
        #pragma unroll
        for (int i = 0; i < (WPB * TVW / 4); i += BLOCK)
            b4[i + tid] = s4[i + tid];
    }
    for (int i = tid; i < 520; i += BLOCK)
        rtab[i] = 1.0f / (float)(i == 0 ? 1 : i);
    __syncthreads();

    if (row < total_rows) {
        const int c = (row / TVH) % TVC;
        float lam = log1pf(expf(lmbd[c]));   // softplus, once per row
        lam = __uint_as_float(__builtin_amdgcn_readfirstlane(__float_as_uint(lam)));
        const float nlam   = -lam;
        const float twolam = 2.0f * lam;
        float* x = buf + wave * TVW;         // in place; prefix [..k0) never re-read

        // Condat (2013) Algorithm 1 state. k = last absorbed index.
        int k = 0, k0 = 0, km = 0, kp = 0, den = 2;   // den = (k+1) - k0 + 1
        float vmin = x[0] - lam, vmax = x[0] + lam;
        float umin = lam, umax = nlam;
        float yn = x[1];                     // prefetched y[k+1]
        float rn = 0.5f;                     // prefetched 1/den (= rtab[2])

        for (int guard = 0; guard < (1 << 16); ++guard) {
            if (k >= TVW - 1) {
                // ---- boundary: k == W-1 (or beyond, degenerate) ----
                int trips = (TVW - 1) - k0;
                if (trips < 0) trips = 0;
                if (__ballot(umin < 0.0f)) {         // flush [k0..km] at vmin
                    const int pe = km < TVW - 1 ? km : TVW - 1;
                    for (int p = k0 + lane; p <= pe; p += 64) x[p] = vmin;
                    k0 = km + 1;
                    km = k0;
                    vmin = x[k0 < TVW ? k0 : TVW - 1];
                    umax = vmin + lam - vmax;
                    umin = lam;
                } else if (__ballot(umax > 0.0f)) {  // flush [k0..kp] at vmax
                    const int pe = kp < TVW - 1 ? kp : TVW - 1;
                    for (int p = k0 + lane; p <= pe; p += 64) x[p] = vmax;
                    k0 = kp + 1;
                    kp = k0;
                    vmax = x[k0 < TVW ? k0 : TVW - 1];
                    umin = vmax + nlam - vmin;
                    umax = nlam;
                } else {                             // terminate: flush tail at mean
                    const float v = vmin + umin * rtab[trips + 1];
                    for (int p = k0 + lane; p < TVW; p += 64) x[p] = v;
                    break;
                }
                k = k0;                              // resume scan from new k0
                yn = x[k0 < TVW ? k0 + 1 : TVW];     // value unused if k0 >= W-1
                rn = 0.5f;
                den = 2;
                continue;
            }

            // ---- absorb element k+1 ----
            const float yn_nx = x[k + 2];            // prefetch (pad-safe)
            const float rn_nx = rtab[den + 1];       // den+1 <= 514
            const float umin_t = umin + yn - vmin;
            const float umax_t = umax + yn - vmax;

            if (__ballot(fmaxf(-umin_t, umax_t) > lam)) {
                // ---- mid-row jump at transition k -> k+1 ----
                if (__ballot(umin_t < nlam)) {       // negative jump: flush at vmin
                    for (int p = k0 + lane; p <= km; p += 64) x[p] = vmin;
                    k0 = km + 1;                     // km <= k <= W-2
                    km = kp = k0;
                    vmin = x[k0];
                    vmax = vmin + twolam;
                } else {                             // positive jump: flush at vmax
                    for (int p = k0 + lane; p <= kp; p += 64) x[p] = vmax;
                    k0 = kp + 1;
                    km = kp = k0;
                    vmax = x[k0];
                    vmin = vmax - twolam;
                }
                umin = lam;
                umax = nlam;
                k = k0;
                yn = x[k0 + 1];                      // pad-safe (k0 <= W-1)
                rn = 0.5f;
                den = 2;
                continue;
            }

            // ---- extend current segment ----
            const int kn = k + 1;
            km = __ballot(umin_t >= lam)  ? kn : km; // uniform -> SALU cselect
            kp = __ballot(umax_t <= nlam) ? kn : kp;
            const float umin_n = fminf(umin_t, lam);
            const float umax_n = fmaxf(umax_t, nlam);
            vmin = fmaf(umin_t - umin_n, rn, vmin);  // == fma(max(umin_t-lam,0),rn,vmin)
            vmax = fmaf(umax_t - umax_n, rn, vmax);  // == fma(min(umax_t+lam,0),rn,vmax)
            umin = umin_n;
            umax = umax_n;
            k = kn;
            den = den + 1;
            yn = yn_nx;
            rn = rn_nx;
        }
    }
    __syncthreads();

    // ---- coalesced float4 writeback LDS -> out ----
    {
        float4* b4 = (float4*)buf;
        float4* d4 = (float4*)(out + (size_t)base_row * TVW);
        #pragma unroll
        for (int i = 0; i < (WPB * TVW / 4); i += BLOCK)
            d4[i + tid] = b4[i + tid];
    }
}

extern "C" void kernel_launch(void* const* d_in, const int* in_sizes, int n_in,
                              void* d_out, int out_size, void* d_ws, size_t ws_size,
                              hipStream_t stream) {
    const float* y    = (const float*)d_in[0];
    const float* lmbd = (const float*)d_in[1];
    float* out = (float*)d_out;

    const int total_rows = in_sizes[0] / TVW;              // 6144
    const int grid = (total_rows + WPB - 1) / WPB;         // 3072 blocks
    tv1d_condat_wave_kernel<<<grid, BLOCK, 0, stream>>>(y, lmbd, out, total_rows);
}

// Round 2
// 276.246 us; speedup vs baseline: 1.2826x; 1.2826x over previous
//
#include <hip/hip_runtime.h>
#include <math.h>

// Problem constants: y is (8, 3, 256, 512) fp32, lmbd is (1,3).
#define TVW 512      // row length
#define TVH 256      // H (for channel index)
#define TVC 3        // channels
#define WPB 2        // waves (= rows) per block; 3072 blocks -> 12 blk/CU, 24 waves/CU
#define BLOCK (WPB * 64)

// One wave per row; all 64 lanes redundantly run the same row's Condat state
// machine. v5 = round-0 structure (counted inner loop, single ballot-break --
// this is what keeps ds_reads pipelined and VALUBusy ~91%; flattening it
// dropped VALUBusy to 51% and regressed) + instruction diet:
//  - clamp adjust without compares: g = u_t - clamp(u_t) (bitwise-identical)
//  - jump detect: single fmax(-umin_t, umax_t) > lam (v_max neg-mod + v_cmp)
//  - km/kp/k0 wave-uniform in SGPRs via __ballot selects -> s_cselect;
//    k0 scalar also kills the per-event readfirstlane(trips)
//  - rn reset after events is the literal 0.5f (was rtab[2] LDS read)
// Output built in place in the LDS row; one coalesced float4 writeback.
__global__ __launch_bounds__(BLOCK)
void tv1d_condat_wave_kernel(const float* __restrict__ y,
                             const float* __restrict__ lmbd,
                             float* __restrict__ out,
                             int total_rows) {
    __shared__ __align__(16) float buf[WPB * TVW + 4];
    __shared__ float rtab[520];        // rtab[i] = 1/i (i>=1)
    const int tid  = threadIdx.x;
    const int wave = tid >> 6;
    const int lane = tid & 63;
    const int base_row = blockIdx.x * WPB;
    const int row = base_row + wave;

    // ---- stage WPB contiguous rows into LDS (coalesced float4) + recip table ----
    {
        float4* b4 = (float4*)buf;
        const float4* s4 = (const float4*)(y + (size_t)base_row * TVW);
        #pragma unroll
        for (int i = 0; i < (WPB * TVW / 4); i += BLOCK)
            b4[i + tid] = s4[i + tid];
    }
    for (int i = tid; i < 520; i += BLOCK)
        rtab[i] = 1.0f / (float)(i == 0 ? 1 : i);
    __syncthreads();

    if (row < total_rows) {
        const int c = (row / TVH) % TVC;
        float lam = log1pf(expf(lmbd[c]));   // softplus, once per row
        lam = __uint_as_float(__builtin_amdgcn_readfirstlane(__float_as_uint(lam)));
        const float nlam   = -lam;
        const float twolam = 2.0f * lam;
        float* x = buf + wave * TVW;         // in place; prefix [..k0) never re-read

        // Condat (2013) Algorithm 1 state. Inner loop always entered with k==k0.
        // k0/km/kp are wave-uniform scalars (ballot-selected -> SGPR/SALU).
        int k0 = 0, km = 0, kp = 0;
        float vmin = x[0] - lam, vmax = x[0] + lam;
        float umin = lam, umax = nlam;

        for (int guard = 0; guard < 4096; ++guard) {
            int trips = (TVW - 1) - k0;      // k0 scalar -> trips scalar
            if (trips < 0) trips = 0;

            float yn = x[k0 + 1];            // pad-safe even if k0 == W-1
            float rn = 0.5f;                 // rn = 1/(t+2), t=0
            const float* xpp = x + (k0 + 2);
            const float* rpp = rtab + 3;
            const int kb = k0 + 1;           // k after extend at trip t: kb + t

            float umin_t = 0.0f, umax_t = 0.0f;
            int t = 0;
            for (; t < trips; ++t) {
                const float yn2 = xpp[t];    // x[k0+2+t], pad-safe
                const float rn2 = rpp[t];    // rtab[3+t] = 1/(t+3)
                umin_t = umin + yn - vmin;
                umax_t = umax + yn - vmax;
                // jump iff umin_t < -lam or umax_t > lam
                if (__ballot(fmaxf(-umin_t, umax_t) > lam)) break;
                const int kc = kb + t;
                km = __ballot(umin_t >= lam)  ? kc : km;   // uniform -> s_cselect
                kp = __ballot(umax_t <= nlam) ? kc : kp;
                const float umin_n = fminf(umin_t, lam);
                const float umax_n = fmaxf(umax_t, nlam);
                vmin = fmaf(umin_t - umin_n, rn, vmin);    // == fma(max(umin_t-lam,0),rn,vmin)
                vmax = fmaf(umax_t - umax_n, rn, vmax);    // == fma(min(umax_t+lam,0),rn,vmax)
                umin = umin_n;
                umax = umax_n;
                yn = yn2; rn = rn2;
            }

            if (t < trips) {
                // ---- mid-row jump at transition k=k0+t -> k+1 ----
                if (__ballot(umin_t < nlam)) {   // negative jump: flush [k0..km] at vmin
                    for (int p = k0 + lane; p <= km; p += 64) x[p] = vmin;
                    k0 = km + 1;             // km <= W-2 here
                    km = kp = k0;
                    vmin = x[k0];
                    vmax = vmin + twolam;
                } else {                     // positive jump: flush [k0..kp] at vmax
                    for (int p = k0 + lane; p <= kp; p += 64) x[p] = vmax;
                    k0 = kp + 1;
                    km = kp = k0;
                    vmax = x[k0];
                    vmin = vmax - twolam;
                }
                umin = lam; umax = nlam;
            } else {
                // ---- boundary: k == W-1, den = trips+1 ----
                if (__ballot(umin < 0.0f)) {     // flush [k0..km] at vmin; keep kp,vmax
                    const int pe = km < TVW - 1 ? km : TVW - 1;
                    for (int p = k0 + lane; p <= pe; p += 64) x[p] = vmin;
                    k0 = km + 1;
                    km = k0;
                    vmin = x[k0 < TVW ? k0 : TVW - 1];
                    umax = vmin + lam - vmax;
                    umin = lam;
                } else if (__ballot(umax > 0.0f)) { // flush [k0..kp] at vmax; keep km,vmin
                    const int pe = kp < TVW - 1 ? kp : TVW - 1;
                    for (int p = k0 + lane; p <= pe; p += 64) x[p] = vmax;
                    k0 = kp + 1;
                    kp = k0;
                    vmax = x[k0 < TVW ? k0 : TVW - 1];
                    umin = vmax + nlam - vmin;
                    umax = nlam;
                } else {                     // terminate: flush tail at mean value
                    const float v = vmin + umin * rtab[trips + 1];
                    for (int p = k0 + lane; p < TVW; p += 64) x[p] = v;
                    break;
                }
            }
        }
    }
    __syncthreads();

    // ---- coalesced float4 writeback LDS -> out ----
    {
        float4* b4 = (float4*)buf;
        float4* d4 = (float4*)(out + (size_t)base_row * TVW);
        #pragma unroll
        for (int i = 0; i < (WPB * TVW / 4); i += BLOCK)
            d4[i + tid] = b4[i + tid];
    }
}

extern "C" void kernel_launch(void* const* d_in, const int* in_sizes, int n_in,
                              void* d_out, int out_size, void* d_ws, size_t ws_size,
                              hipStream_t stream) {
    const float* y    = (const float*)d_in[0];
    const float* lmbd = (const float*)d_in[1];
    float* out = (float*)d_out;

    const int total_rows = in_sizes[0] / TVW;              // 6144
    const int grid = (total_rows + WPB - 1) / WPB;         // 3072 blocks
    tv1d_condat_wave_kernel<<<grid, BLOCK, 0, stream>>>(y, lmbd, out, total_rows);
}